// Round 1
// baseline (5053.352 us; speedup 1.0000x reference)
//
#include <hip/hip_runtime.h>
#include <hip/hip_fp16.h>

typedef _Float16 f16;
typedef _Float16 f16x8 __attribute__((ext_vector_type(8)));
typedef float f32x4 __attribute__((ext_vector_type(4)));

#define DEV static __device__ __forceinline__

// Barrier that waits LDS ops only — keeps prefetch global loads in flight
// (plain __syncthreads() drains vmcnt(0), killing cross-step prefetch).
DEV void lds_barrier() {
  asm volatile("s_waitcnt lgkmcnt(0)" ::: "memory");
  __builtin_amdgcn_s_barrier();
  asm volatile("" ::: "memory");
}

// ---------------------------------------------------------------- conv1
// in [4,2048,80,1] -> out [4,1024,40,64], 3x3 stride2 SAME (pad lo=0 hi=1), relu
__global__ __launch_bounds__(256) void k_conv1(
    const float* __restrict__ in, const float* __restrict__ w,
    const float* __restrict__ bias, float* __restrict__ out)
{
  int idx = blockIdx.x*256 + threadIdx.x;       // 10,485,760 total
  int co = idx & 63;
  int ow = (idx >> 6) % 40;
  int oh = ((idx >> 6) / 40) % 1024;
  int b  = idx / (64*40*1024);
  float acc = bias[co];
#pragma unroll
  for (int kh=0; kh<3; kh++) {
    int ih = oh*2 + kh;
    if (ih >= 2048) continue;
#pragma unroll
    for (int kw=0; kw<3; kw++) {
      int iw = ow*2 + kw;
      if (iw >= 80) continue;
      acc += in[(b*2048 + ih)*80 + iw] * w[(kh*3+kw)*64 + co];
    }
  }
  out[idx] = fmaxf(acc, 0.f);
}

// ---------------------------------------------------------------- conv2
// in [4,1024,40,64] -> out [4,512,20,64], 3x3x64 stride2 SAME, relu
__global__ __launch_bounds__(256) void k_conv2(
    const float* __restrict__ in, const float* __restrict__ w,
    const float* __restrict__ bias, float* __restrict__ out)
{
  __shared__ float xs[3][41][64];
  int bh = blockIdx.x;               // b*512 + oh
  int b = bh >> 9, oh = bh & 511;
  int tid = threadIdx.x;
  for (int idx = tid; idx < 3*41*64; idx += 256) {
    int ci = idx & 63;
    int iw = (idx >> 6) % 41;
    int kh = (idx >> 6) / 41;
    int ih = oh*2 + kh;
    float v = 0.f;
    if (ih < 1024 && iw < 40) v = in[((b*1024 + ih)*40 + iw)*64 + ci];
    xs[kh][iw][ci] = v;
  }
  __syncthreads();
  int co = tid & 63;
  int og = tid >> 6;                 // ow = og*5 + r
  float acc[5];
#pragma unroll
  for (int r=0;r<5;r++) acc[r] = bias[co];
  for (int kh=0; kh<3; kh++)
    for (int kw=0; kw<3; kw++)
      for (int ci=0; ci<64; ci++) {
        float wv = w[((kh*3+kw)*64 + ci)*64 + co];
#pragma unroll
        for (int r=0;r<5;r++)
          acc[r] += xs[kh][2*(og*5+r)+kw][ci] * wv;   // broadcast read per wave
      }
#pragma unroll
  for (int r=0;r<5;r++) {
    int ow = og*5 + r;
    out[((size_t)(b*512+oh)*20 + ow)*64 + co] = fmaxf(acc[r], 0.f);
  }
}

// ---------------------------------------------------------------- proj
// x [4,512,1280] @ pw [1280,16] + pb -> emb0 [4,512,16]
__global__ __launch_bounds__(256) void k_proj(
    const float* __restrict__ x, const float* __restrict__ pw,
    const float* __restrict__ pb, float* __restrict__ out)
{
  int bt = blockIdx.x;
  int tid = threadIdx.x;
  int j = tid >> 4;      // output 0..15
  int l = tid & 15;      // partial lane
  const float* xr = x + (size_t)bt*1280;
  float s = 0.f;
  for (int k=0; k<80; k++) {
    int f = l + 16*k;
    s += xr[f] * pw[f*16 + j];
  }
  s += __shfl_xor(s, 1, 16); s += __shfl_xor(s, 2, 16);
  s += __shfl_xor(s, 4, 16); s += __shfl_xor(s, 8, 16);
  if (l == 0) out[bt*16 + j] = s + pb[j];
}

// ------------------------------------------- primary caps: maxout conv + mask + squash + LN(lni)
// emb0 [4,512,16] -> out [4,512,16,8]
__global__ __launch_bounds__(128) void k_primary(
    const float* __restrict__ emb0,
    const float* __restrict__ w0, const float* __restrict__ b0,
    const float* __restrict__ w1, const float* __restrict__ b1,
    const float* __restrict__ g, const float* __restrict__ be,
    const int* __restrict__ lens, float* __restrict__ out)
{
  int bt = blockIdx.x;
  int b = bt >> 9, t = bt & 511;
  int tid = threadIdx.x;
  int c = tid & 7, j = tid >> 3;   // j in [0,16)
  __shared__ float rows[3][16];
  __shared__ float red[4];
  if (tid < 48) {
    int kh = tid / 16, jj = tid % 16;
    int ts = t + kh - 1;
    rows[kh][jj] = (ts >= 0 && ts < 512) ? emb0[(b*512+ts)*16 + jj] : 0.f;
  }
  __syncthreads();
  float a0 = b0[c], a1 = b1[c];
#pragma unroll
  for (int kh=0; kh<3; kh++)
#pragma unroll
    for (int kw=0; kw<3; kw++) {
      int jj = j + kw - 1;
      if (jj < 0 || jj >= 16) continue;
      float xv = rows[kh][jj];
      a0 += xv * w0[(kh*3+kw)*8 + c];
      a1 += xv * w1[(kh*3+kw)*8 + c];
    }
  float e = fmaxf(a0, a1);
  int valid = (lens[b] + 3) >> 2;
  if (t >= valid) e = 0.f;
  // squash over c (8 aligned lanes)
  float sq = e*e;
  sq += __shfl_xor(sq, 1, 8); sq += __shfl_xor(sq, 2, 8); sq += __shfl_xor(sq, 4, 8);
  float val = e * (sq / (1.f + sq)) * rsqrtf(sq + 1e-9f);
  // LN over 128
  float s1 = val, s2 = val*val;
#pragma unroll
  for (int m=1;m<64;m<<=1){ s1 += __shfl_xor(s1,m,64); s2 += __shfl_xor(s2,m,64); }
  if ((tid & 63) == 0){ red[(tid>>6)*2] = s1; red[(tid>>6)*2+1] = s2; }
  __syncthreads();
  float S1 = red[0]+red[2], S2 = red[1]+red[3];
  float mean = S1/128.f;
  float var  = S2/128.f - mean*mean;
  out[(size_t)bt*128 + tid] = (val-mean)*rsqrtf(var+1e-3f)*g[tid] + be[tid];
}

// ---------------------------------------------------------------- generic LN over 128
__global__ __launch_bounds__(128) void k_ln128(
    const float* __restrict__ in, const float* __restrict__ g,
    const float* __restrict__ be, float* __restrict__ out)
{
  int bt = blockIdx.x, tid = threadIdx.x;
  float x = in[(size_t)bt*128 + tid];
  __shared__ float red[4];
  float s1 = x, s2 = x*x;
#pragma unroll
  for (int m=1;m<64;m<<=1){ s1 += __shfl_xor(s1,m,64); s2 += __shfl_xor(s2,m,64); }
  if ((tid & 63) == 0){ red[(tid>>6)*2] = s1; red[(tid>>6)*2+1] = s2; }
  __syncthreads();
  float S1 = red[0]+red[2], S2 = red[1]+red[3];
  float mean = S1/128.f;
  float var  = S2/128.f - mean*mean;
  out[(size_t)bt*128 + tid] = (x-mean)*rsqrtf(var+1e-3f)*g[tid] + be[tid];
}

// ---------------------------------------------------------------- u_hat precompute
// src [4,512,16,8]; W [80,CO,CD,8]; B [80,CO,CD] -> out fp16 [4,512,80*CO,CD]
// Wave-uniform (n), lanes = 64 consecutive (b,t) -> W/B become scalar loads.
template<int CO, int CD>
__global__ __launch_bounds__(256) void k_uhat(
    const float* __restrict__ src, const float* __restrict__ W,
    const float* __restrict__ Bs, f16* __restrict__ out)
{
  constexpr int NP = 80*CO;
  int wid = __builtin_amdgcn_readfirstlane(blockIdx.x*4 + (threadIdx.x >> 6));
  int lane = threadIdx.x & 63;
  int n   = wid % 80;
  int btc = wid / 80;            // 0..31
  int bt = btc*64 + lane;        // stays within one b (512 % 64 == 0)
  int b = bt >> 9, t = bt & 511;
  int k = n >> 4, i = n & 15;
  int ts = t + k - 2;
  float x[8];
  if (ts >= 0 && ts < 512) {
    const float* xr = src + ((size_t)(b*512+ts)*16 + i)*8;
    f32x4 x0 = *(const f32x4*)xr;
    f32x4 x1 = *(const f32x4*)(xr+4);
#pragma unroll
    for (int q=0;q<4;q++){ x[q]=x0[q]; x[4+q]=x1[q]; }
  } else {
#pragma unroll
    for (int q=0;q<8;q++) x[q]=0.f;
  }
  const float* Wn = W  + (size_t)n*CO*CD*8;
  const float* Bn = Bs + (size_t)n*CO*CD;
  for (int o=0; o<CO; o++) {
    alignas(16) f16 res[CD];
#pragma unroll
    for (int p=0;p<CD;p++) {
      float a = Bn[o*CD+p];
#pragma unroll
      for (int q=0;q<8;q++) a += Wn[(o*CD+p)*8+q]*x[q];
      res[p] = (f16)a;
    }
    f16* op = out + ((size_t)bt*NP + (size_t)n*CO + o)*CD;
    *(uint4*)op = *(const uint4*)res;
    if constexpr (CD==16) *((uint4*)op+1) = *((const uint4*)res+1);
  }
}

// ---------------------------------------------------------------- routing scan
// uh fp16 [4,T,80*CO,CD] -> vseq [4,T,CO,CD]; one block per batch.
// thread tid: o = tid%CO, j = tid/CO; slot s holds pair e = tid + TH*s  (n = j+16s).
// Row-n softmax lives on CO consecutive lanes -> pure shfl_xor.
template<int CO, int CD, bool MASK>
__global__ __launch_bounds__(CO*16) void k_scan(
    const f16* __restrict__ uh, float* __restrict__ vseq, int T)
{
  constexpr int TH = CO*16;
  constexpr int NP = 80*CO;
  constexpr int NV = CD/8;
  const int b = blockIdx.x;
  const int tid = threadIdx.x;
  const int o = tid % CO;

  __shared__ float part[16*CO*(CD+1)];
  __shared__ float smat[CO*(CD+1)];

  const f16* __restrict__ ub = uh + (size_t)b*T*NP*CD;
  float* __restrict__ vb = vseq + (size_t)b*T*CO*CD;

  float v[CD];
#pragma unroll
  for (int p=0;p<CD;p++) v[p]=0.f;

  f16x8 A[5][NV], Bb[5][NV];

  auto loadu = [&](f16x8 (&U)[5][NV], int tt) {
    const f16* base = ub + (size_t)tt*NP*CD + (size_t)tid*CD;
#pragma unroll
    for (int s=0;s<5;s++)
#pragma unroll
      for (int q=0;q<NV;q++)
        U[s][q] = *(const f16x8*)(base + (size_t)s*TH*CD + q*8);
  };

  auto step = [&](f16x8 (&U)[5][NV], int tt) {
    float pp[CD];
#pragma unroll
    for (int p=0;p<CD;p++) pp[p]=0.f;
#pragma unroll
    for (int s=0;s<5;s++) {
      float uf[CD];
      float lg = 0.f;
#pragma unroll
      for (int q=0;q<NV;q++)
#pragma unroll
        for (int z=0;z<8;z++) {
          float uv = (float)U[s][q][z];
          uf[q*8+z] = uv;
          lg += uv * v[q*8+z];
        }
      if (MASK && o==0) lg += -1e9f;
      float mx = lg;
#pragma unroll
      for (int m=1;m<CO;m<<=1) mx = fmaxf(mx, __shfl_xor(mx, m, CO));
      float ex = __expf(lg - mx);
      float sm = ex;
#pragma unroll
      for (int m=1;m<CO;m<<=1) sm += __shfl_xor(sm, m, CO);
      float cc = ex / sm;
#pragma unroll
      for (int p=0;p<CD;p++) pp[p] += cc * uf[p];
    }
    float* pr = part + tid*(CD+1);
#pragma unroll
    for (int p=0;p<CD;p++) pr[p] = pp[p];
    lds_barrier();
    if (tid < CO*CD) {
      const int so = tid % CO, sp = tid / CO;
      float sv = 0.f;
#pragma unroll
      for (int jj=0;jj<16;jj++) sv += part[(jj*CO+so)*(CD+1)+sp];
      smat[so*(CD+1)+sp] = sv;
    }
    lds_barrier();
    float sq = 0.f;
#pragma unroll
    for (int p=0;p<CD;p++) { float sv = smat[o*(CD+1)+p]; v[p]=sv; sq += sv*sv; }
    float f = (sq/(1.f+sq)) * rsqrtf(sq + 1e-9f);
#pragma unroll
    for (int p=0;p<CD;p++) v[p] *= f;
    if (tid < CO) {
      float* orow = vb + ((size_t)tt*CO + o)*CD;
#pragma unroll
      for (int p=0;p<CD;p+=4) {
        f32x4 w4 = { v[p], v[p+1], v[p+2], v[p+3] };
        *(f32x4*)(orow + p) = w4;
      }
    }
  };

  loadu(A, 0);
  for (int tt=0; tt<T; tt+=2) {
    loadu(Bb, tt+1);          // prefetch t+1 while computing t
    step(A, tt);
    if (tt+2 < T) loadu(A, tt+2);
    step(Bb, tt+1);
  }
}

// ---------------------------------------------------------------- final: LN512 -> length -> LN32
__global__ __launch_bounds__(512) void k_final(
    const float* __restrict__ v1,
    const float* __restrict__ g1, const float* __restrict__ b1,
    const float* __restrict__ g2, const float* __restrict__ b2,
    float* __restrict__ out)
{
  int bt = blockIdx.x;
  int tid = threadIdx.x;
  float x = v1[(size_t)bt*512 + tid];
  __shared__ float red[16];
  __shared__ float Ls[32];
  float s1 = x, s2 = x*x;
#pragma unroll
  for (int m=1;m<64;m<<=1){ s1 += __shfl_xor(s1,m,64); s2 += __shfl_xor(s2,m,64); }
  if ((tid & 63) == 0){ red[(tid>>6)*2] = s1; red[(tid>>6)*2+1] = s2; }
  __syncthreads();
  float S1 = 0.f, S2 = 0.f;
#pragma unroll
  for (int i=0;i<8;i++){ S1 += red[2*i]; S2 += red[2*i+1]; }
  float mean = S1/512.f, var = S2/512.f - mean*mean;
  float y = (x-mean)*rsqrtf(var+1e-3f)*g1[tid] + b1[tid];
  // capsule length over p (16 aligned lanes)
  float ss = y*y;
  ss += __shfl_xor(ss,1,16); ss += __shfl_xor(ss,2,16);
  ss += __shfl_xor(ss,4,16); ss += __shfl_xor(ss,8,16);
  float L = sqrtf(ss + 1e-9f);
  if ((tid & 15) == 0) Ls[tid >> 4] = L;
  __syncthreads();
  if (tid < 32) {
    float l = Ls[tid];
    float t1 = l, t2 = l*l;
#pragma unroll
    for (int m=1;m<32;m<<=1){ t1 += __shfl_xor(t1,m,32); t2 += __shfl_xor(t2,m,32); }
    float mn = t1/32.f, vr = t2/32.f - mn*mn;
    out[(size_t)bt*32 + tid] = (l-mn)*rsqrtf(vr+1e-3f)*g2[tid] + b2[tid];
  }
}

// ---------------------------------------------------------------- launch
static const size_t OFF_X1    = 0;            // 41,943,040 B f32 [4,1024,40,64]
static const size_t OFF_UH0   = 41943040;     // 41,943,040 B f16 [4,512,1280,8]
static const size_t OFF_X2    = 83886080;     // 10,485,760 B f32 [4,512,20,64]
static const size_t OFF_EMB0  = 94371840;     //    131,072 B f32 [4,512,16]
static const size_t OFF_EMBLN = 94502912;     //  1,048,576 B f32 [4,512,16,8]
static const size_t OFF_UH1   = 0;            // 167,772,160 B f16 [4,512,2560,16] (reuses dead X1/UH0/X2/EMB0/EMBLN)
static const size_t OFF_V0    = 167772160;    //  1,048,576 B f32 [4,512,16,8]
static const size_t OFF_V0LN  = 168820736;    //  1,048,576 B f32
static const size_t OFF_V1    = 169869312;    //  4,194,304 B f32 [4,512,32,16]
static const size_t WS_NEED   = 174063616;

extern "C" void kernel_launch(void* const* d_in, const int* in_sizes, int n_in,
                              void* d_out, int out_size, void* d_ws, size_t ws_size,
                              hipStream_t stream) {
  (void)in_sizes; (void)n_in; (void)out_size;
  if (ws_size < WS_NEED) return;   // clean validation fail instead of OOB corruption

  const float* inputs = (const float*)d_in[0];
  const int*   lens   = (const int*)d_in[1];
  const float* c1w=(const float*)d_in[2],  *c1b=(const float*)d_in[3];
  const float* c2w=(const float*)d_in[4],  *c2b=(const float*)d_in[5];
  const float* pw =(const float*)d_in[6],  *pb =(const float*)d_in[7];
  const float* e0w=(const float*)d_in[8],  *e0b=(const float*)d_in[9];
  const float* e1w=(const float*)d_in[10], *e1b=(const float*)d_in[11];
  const float* lnig=(const float*)d_in[12],*lnib=(const float*)d_in[13];
  const float* W0=(const float*)d_in[14],  *B0=(const float*)d_in[15];
  const float* W1=(const float*)d_in[16],  *B1=(const float*)d_in[17];
  const float* lnm0g=(const float*)d_in[18],*lnm0b=(const float*)d_in[19];
  const float* lnm1g=(const float*)d_in[20],*lnm1b=(const float*)d_in[21];
  const float* lnog=(const float*)d_in[22], *lnob=(const float*)d_in[23];

  char* ws = (char*)d_ws;
  float* x1    = (float*)(ws + OFF_X1);
  f16*   uh0   = (f16*)  (ws + OFF_UH0);
  float* x2    = (float*)(ws + OFF_X2);
  float* emb0  = (float*)(ws + OFF_EMB0);
  float* embln = (float*)(ws + OFF_EMBLN);
  f16*   uh1   = (f16*)  (ws + OFF_UH1);
  float* v0    = (float*)(ws + OFF_V0);
  float* v0ln  = (float*)(ws + OFF_V0LN);
  float* v1    = (float*)(ws + OFF_V1);

  k_conv1<<<40960, 256, 0, stream>>>(inputs, c1w, c1b, x1);
  k_conv2<<<2048, 256, 0, stream>>>(x1, c2w, c2b, x2);
  k_proj <<<2048, 256, 0, stream>>>(x2, pw, pb, emb0);
  k_primary<<<2048, 128, 0, stream>>>(emb0, e0w, e0b, e1w, e1b, lnig, lnib, lens, embln);
  k_uhat<16,8><<<640, 256, 0, stream>>>(embln, W0, B0, uh0);
  k_scan<16,8,false><<<4, 256, 0, stream>>>(uh0, v0, 512);
  k_ln128<<<2048, 128, 0, stream>>>(v0, lnm0g, lnm0b, v0ln);
  k_uhat<32,16><<<640, 256, 0, stream>>>(v0ln, W1, B1, uh1);
  k_scan<32,16,true><<<4, 512, 0, stream>>>(uh1, v1, 512);
  k_final<<<2048, 512, 0, stream>>>(v1, lnm1g, lnm1b, lnog, lnob, (float*)d_out);
}

// Round 2
// 2795.391 us; speedup vs baseline: 1.8077x; 1.8077x over previous
//
#include <hip/hip_runtime.h>
#include <hip/hip_fp16.h>

typedef _Float16 f16;
typedef _Float16 f16x8 __attribute__((ext_vector_type(8)));
typedef float f32x4 __attribute__((ext_vector_type(4)));

#define DEV static __device__ __forceinline__

// Barrier that waits LDS ops only — keeps prefetch global loads in flight
// (plain __syncthreads() drains vmcnt(0), killing cross-step prefetch).
DEV void lds_barrier() {
  asm volatile("s_waitcnt lgkmcnt(0)" ::: "memory");
  __builtin_amdgcn_s_barrier();
  asm volatile("" ::: "memory");
}

// ---------------------------------------------------------------- conv1
// in [4,2048,80,1] -> out f16 [4,1024,40,64], 3x3 stride2 SAME, relu
__global__ __launch_bounds__(256) void k_conv1(
    const float* __restrict__ in, const float* __restrict__ w,
    const float* __restrict__ bias, f16* __restrict__ out)
{
  int idx = blockIdx.x*256 + threadIdx.x;       // 10,485,760 total
  int co = idx & 63;
  int ow = (idx >> 6) % 40;
  int oh = ((idx >> 6) / 40) % 1024;
  int b  = idx / (64*40*1024);
  float acc = bias[co];
#pragma unroll
  for (int kh=0; kh<3; kh++) {
    int ih = oh*2 + kh;
    if (ih >= 2048) continue;
#pragma unroll
    for (int kw=0; kw<3; kw++) {
      int iw = ow*2 + kw;
      if (iw >= 80) continue;
      acc += in[(b*2048 + ih)*80 + iw] * w[(kh*3+kw)*64 + co];
    }
  }
  out[idx] = (f16)fmaxf(acc, 0.f);
}

// ---------------------------------------------------------------- weight convert+transpose
// w f32 [576 k][64 co] -> wt f16 [64 n][600 k] (zero-padded), linear 38912 elems
__global__ __launch_bounds__(256) void k_wcvt(
    const float* __restrict__ w, f16* __restrict__ wt)
{
  int idx = blockIdx.x*256 + threadIdx.x;
  if (idx >= 38912) return;
  f16 v = (f16)0.f;
  if (idx < 38400) {
    int n = idx / 600, k = idx % 600;
    if (k < 576) v = (f16)w[k*64 + n];
  }
  wt[idx] = v;
}

// ---------------------------------------------------------------- conv2 as implicit GEMM (MFMA fp16)
// x1f f16 [4,1024,40,64]; wt f16 [64][600]; out f32 [4,512,20,64]
// M=40960 rows (b,oh,ow), N=64, K=576. Block: 256 thr = 4 waves, tile 128x64.
__global__ __launch_bounds__(256) void k_conv2m(
    const f16* __restrict__ x1f, const f16* __restrict__ wt,
    const float* __restrict__ bias, float* __restrict__ out)
{
  __shared__ f16 Bt[38912];   // [64][600] padded to 77,824 B
  const int tid = threadIdx.x;
  // stage all weights global->LDS (19 x 4KB, linear)
  for (int it = 0; it < 19; ++it) {
    const f16* g = wt + it*2048 + tid*8;
    f16* l = Bt + it*2048 + tid*8;
    __builtin_amdgcn_global_load_lds(
        (const __attribute__((address_space(1))) void*)g,
        (__attribute__((address_space(3))) void*)l, 16, 0, 0);
  }
  __syncthreads();

  const int wave = tid >> 6, l = tid & 63;
  const int lrow = l & 15, lk = l >> 4;     // lk in 0..3
  const int m0 = blockIdx.x*128 + wave*32;

  const int mA = m0 + lrow, mB = m0 + 16 + lrow;
  int bA = mA/10240, rA = mA%10240, ohA = rA/20, owA = rA%20;
  int bB = mB/10240, rB = mB%10240, ohB = rB/20, owB = rB%20;
  const f16* pA = x1f + ((size_t)((bA*1024 + ohA*2)*40 + owA*2))*64;
  const f16* pB = x1f + ((size_t)((bB*1024 + ohB*2)*40 + owB*2))*64;

  f32x4 acc[2][4];
#pragma unroll
  for (int i=0;i<2;i++)
#pragma unroll
    for (int j=0;j<4;j++) acc[i][j] = (f32x4){0.f,0.f,0.f,0.f};

  const f16x8 zero8 = {};
#pragma unroll
  for (int kk=0; kk<18; ++kk) {
    const int tap = kk >> 1;
    const int kh = tap/3, kw = tap%3;
    const int ci0 = ((kk&1)<<5) + lk*8;
    const int off = (kh*40 + kw)*64 + ci0;
    const bool okA = (ohA*2+kh < 1024) && (owA*2+kw < 40);
    const bool okB = (ohB*2+kh < 1024) && (owB*2+kw < 40);
    f16x8 a0 = okA ? *(const f16x8*)(pA + off) : zero8;
    f16x8 a1 = okB ? *(const f16x8*)(pB + off) : zero8;
#pragma unroll
    for (int nf=0; nf<4; ++nf) {
      f16x8 bb = *(const f16x8*)&Bt[(nf*16 + lrow)*600 + kk*32 + lk*8];
      acc[0][nf] = __builtin_amdgcn_mfma_f32_16x16x32_f16(a0, bb, acc[0][nf], 0,0,0);
      acc[1][nf] = __builtin_amdgcn_mfma_f32_16x16x32_f16(a1, bb, acc[1][nf], 0,0,0);
    }
  }
  // C/D: col = l&15, row = lk*4 + r
#pragma unroll
  for (int nf=0; nf<4; ++nf) {
    const int n = nf*16 + lrow;
    const float bi = bias[n];
#pragma unroll
    for (int mf=0; mf<2; ++mf)
#pragma unroll
      for (int r=0; r<4; ++r) {
        int mrow = m0 + mf*16 + lk*4 + r;
        out[(size_t)mrow*64 + n] = fmaxf(acc[mf][nf][r] + bi, 0.f);
      }
  }
}

// ---------------------------------------------------------------- proj
// x [4,512,1280] @ pw [1280,16] + pb -> emb0 [4,512,16]
__global__ __launch_bounds__(256) void k_proj(
    const float* __restrict__ x, const float* __restrict__ pw,
    const float* __restrict__ pb, float* __restrict__ out)
{
  int bt = blockIdx.x;
  int tid = threadIdx.x;
  int j = tid >> 4;      // output 0..15
  int l = tid & 15;      // partial lane
  const float* xr = x + (size_t)bt*1280;
  float s = 0.f;
  for (int k=0; k<80; k++) {
    int f = l + 16*k;
    s += xr[f] * pw[f*16 + j];
  }
  s += __shfl_xor(s, 1, 16); s += __shfl_xor(s, 2, 16);
  s += __shfl_xor(s, 4, 16); s += __shfl_xor(s, 8, 16);
  if (l == 0) out[bt*16 + j] = s + pb[j];
}

// ------------------------------------------- primary caps: maxout conv + mask + squash + LN(lni)
__global__ __launch_bounds__(128) void k_primary(
    const float* __restrict__ emb0,
    const float* __restrict__ w0, const float* __restrict__ b0,
    const float* __restrict__ w1, const float* __restrict__ b1,
    const float* __restrict__ g, const float* __restrict__ be,
    const int* __restrict__ lens, float* __restrict__ out)
{
  int bt = blockIdx.x;
  int b = bt >> 9, t = bt & 511;
  int tid = threadIdx.x;
  int c = tid & 7, j = tid >> 3;   // j in [0,16)
  __shared__ float rows[3][16];
  __shared__ float red[4];
  if (tid < 48) {
    int kh = tid / 16, jj = tid % 16;
    int ts = t + kh - 1;
    rows[kh][jj] = (ts >= 0 && ts < 512) ? emb0[(b*512+ts)*16 + jj] : 0.f;
  }
  __syncthreads();
  float a0 = b0[c], a1 = b1[c];
#pragma unroll
  for (int kh=0; kh<3; kh++)
#pragma unroll
    for (int kw=0; kw<3; kw++) {
      int jj = j + kw - 1;
      if (jj < 0 || jj >= 16) continue;
      float xv = rows[kh][jj];
      a0 += xv * w0[(kh*3+kw)*8 + c];
      a1 += xv * w1[(kh*3+kw)*8 + c];
    }
  float e = fmaxf(a0, a1);
  int valid = (lens[b] + 3) >> 2;
  if (t >= valid) e = 0.f;
  float sq = e*e;
  sq += __shfl_xor(sq, 1, 8); sq += __shfl_xor(sq, 2, 8); sq += __shfl_xor(sq, 4, 8);
  float val = e * (sq / (1.f + sq)) * rsqrtf(sq + 1e-9f);
  float s1 = val, s2 = val*val;
#pragma unroll
  for (int m=1;m<64;m<<=1){ s1 += __shfl_xor(s1,m,64); s2 += __shfl_xor(s2,m,64); }
  if ((tid & 63) == 0){ red[(tid>>6)*2] = s1; red[(tid>>6)*2+1] = s2; }
  __syncthreads();
  float S1 = red[0]+red[2], S2 = red[1]+red[3];
  float mean = S1/128.f;
  float var  = S2/128.f - mean*mean;
  out[(size_t)bt*128 + tid] = (val-mean)*rsqrtf(var+1e-3f)*g[tid] + be[tid];
}

// ---------------------------------------------------------------- generic LN over 128
__global__ __launch_bounds__(128) void k_ln128(
    const float* __restrict__ in, const float* __restrict__ g,
    const float* __restrict__ be, float* __restrict__ out)
{
  int bt = blockIdx.x, tid = threadIdx.x;
  float x = in[(size_t)bt*128 + tid];
  __shared__ float red[4];
  float s1 = x, s2 = x*x;
#pragma unroll
  for (int m=1;m<64;m<<=1){ s1 += __shfl_xor(s1,m,64); s2 += __shfl_xor(s2,m,64); }
  if ((tid & 63) == 0){ red[(tid>>6)*2] = s1; red[(tid>>6)*2+1] = s2; }
  __syncthreads();
  float S1 = red[0]+red[2], S2 = red[1]+red[3];
  float mean = S1/128.f;
  float var  = S2/128.f - mean*mean;
  out[(size_t)bt*128 + tid] = (x-mean)*rsqrtf(var+1e-3f)*g[tid] + be[tid];
}

// ---------------------------------------------------------------- u_hat precompute
template<int CO, int CD>
__global__ __launch_bounds__(256) void k_uhat(
    const float* __restrict__ src, const float* __restrict__ W,
    const float* __restrict__ Bs, f16* __restrict__ out)
{
  constexpr int NP = 80*CO;
  int wid = __builtin_amdgcn_readfirstlane(blockIdx.x*4 + (threadIdx.x >> 6));
  int lane = threadIdx.x & 63;
  int n   = wid % 80;
  int btc = wid / 80;            // 0..31
  int bt = btc*64 + lane;
  int b = bt >> 9, t = bt & 511;
  int k = n >> 4, i = n & 15;
  int ts = t + k - 2;
  float x[8];
  if (ts >= 0 && ts < 512) {
    const float* xr = src + ((size_t)(b*512+ts)*16 + i)*8;
    f32x4 x0 = *(const f32x4*)xr;
    f32x4 x1 = *(const f32x4*)(xr+4);
#pragma unroll
    for (int q=0;q<4;q++){ x[q]=x0[q]; x[4+q]=x1[q]; }
  } else {
#pragma unroll
    for (int q=0;q<8;q++) x[q]=0.f;
  }
  const float* Wn = W  + (size_t)n*CO*CD*8;
  const float* Bn = Bs + (size_t)n*CO*CD;
  for (int o=0; o<CO; o++) {
    alignas(16) f16 res[CD];
#pragma unroll
    for (int p=0;p<CD;p++) {
      float a = Bn[o*CD+p];
#pragma unroll
      for (int q=0;q<8;q++) a += Wn[(o*CD+p)*8+q]*x[q];
      res[p] = (f16)a;
    }
    f16* op = out + ((size_t)bt*NP + (size_t)n*CO + o)*CD;
    *(uint4*)op = *(const uint4*)res;
    if constexpr (CD==16) *((uint4*)op+1) = *((const uint4*)res+1);
  }
}

// ---------------------------------------------------------------- routing scan
// uh fp16 [4,T,80*CO,CD] -> vseq [4,T,CO,CD]; one block per batch.
// 3-deep register prefetch pipeline (named buffers, rule-#20 safe).
template<int CO, int CD, bool MASK>
__global__ __launch_bounds__(CO*16) void k_scan(
    const f16* __restrict__ uh, float* __restrict__ vseq, int T)
{
  constexpr int TH = CO*16;
  constexpr int NP = 80*CO;
  constexpr int NV = CD/8;
  const int b = blockIdx.x;
  const int tid = threadIdx.x;
  const int o = tid % CO;

  __shared__ float part[16*CO*(CD+1)];
  __shared__ float smat[CO*(CD+1)];

  const f16* __restrict__ ub = uh + (size_t)b*T*NP*CD;
  float* __restrict__ vb = vseq + (size_t)b*T*CO*CD;

  float v[CD];
#pragma unroll
  for (int p=0;p<CD;p++) v[p]=0.f;

  f16x8 A[5][NV], Bb[5][NV], Cc[5][NV];

  auto loadu = [&](f16x8 (&U)[5][NV], int tt) {
    const f16* base = ub + (size_t)tt*NP*CD + (size_t)tid*CD;
#pragma unroll
    for (int s=0;s<5;s++)
#pragma unroll
      for (int q=0;q<NV;q++)
        U[s][q] = *(const f16x8*)(base + (size_t)s*TH*CD + q*8);
  };

  auto step = [&](f16x8 (&U)[5][NV], int tt) {
    float pp[CD];
#pragma unroll
    for (int p=0;p<CD;p++) pp[p]=0.f;
#pragma unroll
    for (int s=0;s<5;s++) {
      float uf[CD];
      float lg = 0.f;
#pragma unroll
      for (int q=0;q<NV;q++)
#pragma unroll
        for (int z=0;z<8;z++) {
          float uv = (float)U[s][q][z];
          uf[q*8+z] = uv;
          lg += uv * v[q*8+z];
        }
      if (MASK && o==0) lg += -1e9f;
      float mx = lg;
#pragma unroll
      for (int m=1;m<CO;m<<=1) mx = fmaxf(mx, __shfl_xor(mx, m, CO));
      float ex = __expf(lg - mx);
      float sm = ex;
#pragma unroll
      for (int m=1;m<CO;m<<=1) sm += __shfl_xor(sm, m, CO);
      float cc = ex / sm;
#pragma unroll
      for (int p=0;p<CD;p++) pp[p] += cc * uf[p];
    }
    float* pr = part + tid*(CD+1);
#pragma unroll
    for (int p=0;p<CD;p++) pr[p] = pp[p];
    lds_barrier();
    if (tid < CO*CD) {
      const int so = tid % CO, sp = tid / CO;
      float sv = 0.f;
#pragma unroll
      for (int jj=0;jj<16;jj++) sv += part[(jj*CO+so)*(CD+1)+sp];
      smat[so*(CD+1)+sp] = sv;
    }
    lds_barrier();
    float sq = 0.f;
#pragma unroll
    for (int p=0;p<CD;p++) { float sv = smat[o*(CD+1)+p]; v[p]=sv; sq += sv*sv; }
    float f = (sq/(1.f+sq)) * rsqrtf(sq + 1e-9f);
#pragma unroll
    for (int p=0;p<CD;p++) v[p] *= f;
    if (tid < CO) {
      float* orow = vb + ((size_t)tt*CO + o)*CD;
#pragma unroll
      for (int p=0;p<CD;p+=4) {
        f32x4 w4 = { v[p], v[p+1], v[p+2], v[p+3] };
        *(f32x4*)(orow + p) = w4;
      }
    }
  };

  auto cl = [&](int t)->int { return t < T ? t : T-1; };

  loadu(A, 0); loadu(Bb, cl(1));
  for (int tt = 0; tt < T; tt += 3) {
    loadu(Cc, cl(tt+2));
    step(A, tt);
    if (tt+1 >= T) break;
    loadu(A, cl(tt+3));
    step(Bb, tt+1);
    if (tt+2 >= T) break;
    loadu(Bb, cl(tt+4));
    step(Cc, tt+2);
  }
}

// ---------------------------------------------------------------- final: LN512 -> length -> LN32
__global__ __launch_bounds__(512) void k_final(
    const float* __restrict__ v1,
    const float* __restrict__ g1, const float* __restrict__ b1,
    const float* __restrict__ g2, const float* __restrict__ b2,
    float* __restrict__ out)
{
  int bt = blockIdx.x;
  int tid = threadIdx.x;
  float x = v1[(size_t)bt*512 + tid];
  __shared__ float red[16];
  __shared__ float Ls[32];
  float s1 = x, s2 = x*x;
#pragma unroll
  for (int m=1;m<64;m<<=1){ s1 += __shfl_xor(s1,m,64); s2 += __shfl_xor(s2,m,64); }
  if ((tid & 63) == 0){ red[(tid>>6)*2] = s1; red[(tid>>6)*2+1] = s2; }
  __syncthreads();
  float S1 = 0.f, S2 = 0.f;
#pragma unroll
  for (int i=0;i<8;i++){ S1 += red[2*i]; S2 += red[2*i+1]; }
  float mean = S1/512.f, var = S2/512.f - mean*mean;
  float y = (x-mean)*rsqrtf(var+1e-3f)*g1[tid] + b1[tid];
  float ss = y*y;
  ss += __shfl_xor(ss,1,16); ss += __shfl_xor(ss,2,16);
  ss += __shfl_xor(ss,4,16); ss += __shfl_xor(ss,8,16);
  float L = sqrtf(ss + 1e-9f);
  if ((tid & 15) == 0) Ls[tid >> 4] = L;
  __syncthreads();
  if (tid < 32) {
    float l = Ls[tid];
    float t1 = l, t2 = l*l;
#pragma unroll
    for (int m=1;m<32;m<<=1){ t1 += __shfl_xor(t1,m,32); t2 += __shfl_xor(t2,m,32); }
    float mn = t1/32.f, vr = t2/32.f - mn*mn;
    out[(size_t)bt*32 + tid] = (l-mn)*rsqrtf(vr+1e-3f)*g2[tid] + b2[tid];
  }
}

// ---------------------------------------------------------------- workspace layout
// region [0, 167,772,160) is reused by uh1 after the frontend is done.
static const size_t OFF_X1F   = 0;            // 20,971,520 B f16 [4,1024,40,64]
static const size_t OFF_WT16  = 20971520;     //     77,824 B f16 [64][600] padded
static const size_t OFF_X2    = 21049344;     // 10,485,760 B f32 [4,512,20,64]
static const size_t OFF_EMB0  = 31535104;     //    131,072 B f32 [4,512,16]
static const size_t OFF_UH0   = 31666176;     // 41,943,040 B f16 [4,512,1280,8]
static const size_t OFF_UH1   = 0;            // 167,772,160 B f16 [4,512,2560,16]
static const size_t OFF_EMBLN = 167772160;    //  1,048,576 B f32 (dead before scan0)
static const size_t OFF_V0    = 167772160;    //  1,048,576 B f32 (reuses EMBLN slot)
static const size_t OFF_V0LN  = 168820736;    //  1,048,576 B f32
static const size_t OFF_V1    = 169869312;    //  4,194,304 B f32 [4,512,32,16]
static const size_t WS_NEED   = 174063616;

extern "C" void kernel_launch(void* const* d_in, const int* in_sizes, int n_in,
                              void* d_out, int out_size, void* d_ws, size_t ws_size,
                              hipStream_t stream) {
  (void)in_sizes; (void)n_in; (void)out_size;
  if (ws_size < WS_NEED) return;

  const float* inputs = (const float*)d_in[0];
  const int*   lens   = (const int*)d_in[1];
  const float* c1w=(const float*)d_in[2],  *c1b=(const float*)d_in[3];
  const float* c2w=(const float*)d_in[4],  *c2b=(const float*)d_in[5];
  const float* pw =(const float*)d_in[6],  *pb =(const float*)d_in[7];
  const float* e0w=(const float*)d_in[8],  *e0b=(const float*)d_in[9];
  const float* e1w=(const float*)d_in[10], *e1b=(const float*)d_in[11];
  const float* lnig=(const float*)d_in[12],*lnib=(const float*)d_in[13];
  const float* W0=(const float*)d_in[14],  *B0=(const float*)d_in[15];
  const float* W1=(const float*)d_in[16],  *B1=(const float*)d_in[17];
  const float* lnm0g=(const float*)d_in[18],*lnm0b=(const float*)d_in[19];
  const float* lnm1g=(const float*)d_in[20],*lnm1b=(const float*)d_in[21];
  const float* lnog=(const float*)d_in[22], *lnob=(const float*)d_in[23];

  char* ws = (char*)d_ws;
  f16*   x1f   = (f16*)  (ws + OFF_X1F);
  f16*   wt16  = (f16*)  (ws + OFF_WT16);
  float* x2    = (float*)(ws + OFF_X2);
  float* emb0  = (float*)(ws + OFF_EMB0);
  f16*   uh0   = (f16*)  (ws + OFF_UH0);
  f16*   uh1   = (f16*)  (ws + OFF_UH1);
  float* embln = (float*)(ws + OFF_EMBLN);
  float* v0    = (float*)(ws + OFF_V0);
  float* v0ln  = (float*)(ws + OFF_V0LN);
  float* v1    = (float*)(ws + OFF_V1);

  k_conv1<<<40960, 256, 0, stream>>>(inputs, c1w, c1b, x1f);
  k_wcvt <<<152, 256, 0, stream>>>(c2w, wt16);
  k_conv2m<<<320, 256, 0, stream>>>(x1f, wt16, c2b, x2);
  k_proj <<<2048, 256, 0, stream>>>(x2, pw, pb, emb0);
  k_primary<<<2048, 128, 0, stream>>>(emb0, e0w, e0b, e1w, e1b, lnig, lnib, lens, embln);
  k_uhat<16,8><<<640, 256, 0, stream>>>(embln, W0, B0, uh0);
  k_scan<16,8,false><<<4, 256, 0, stream>>>(uh0, v0, 512);
  k_ln128<<<2048, 128, 0, stream>>>(v0, lnm0g, lnm0b, v0ln);
  k_uhat<32,16><<<640, 256, 0, stream>>>(v0ln, W1, B1, uh1);
  k_scan<32,16,true><<<4, 512, 0, stream>>>(uh1, v1, 512);
  k_final<<<2048, 512, 0, stream>>>(v1, lnm1g, lnm1b, lnog, lnob, (float*)d_out);
}